// Round 6
// baseline (106.124 us; speedup 1.0000x reference)
//
#include <hip/hip_runtime.h>

// LearnedTaskSpecificLinear: out[n,o] = sum_i x[n,i] * W[task_ids[n], i, o]
// x: [2048,512] f32, task_ids: [2048] i32, W: [64,512,512] f32, out: [2048,512] f32
//
// Round 10: BARRIER-FREE wave-per-unit restructure.
//   R9 counters showed the kernel is latency/duty-cycle bound (41 MB HBM,
//   ~1.7 TB/s effective, L3-resident inputs), not BW-bound: the lockstep
//   barrier schedule idles the CU at every drain. Fix: one wave owns one
//   unit (task x 32-col chunk) end-to-end with a PRIVATE 32 KB LDS region;
//   there is NO __syncthreads / s_barrier anywhere. Same-wave ds ordering
//   is handled by lgkmcnt (compiler-inserted).
//   grid 256 blocks x 256 thr (4 waves) = 1024 waves = 1024 units, 1 block/CU
//   (LDS 4x32KB + lists = 133 KB). Decode: task = (bid&7)|((bid>>5)<<3) so a
//   task's 4 blocks share one XCD -> x rows L2-resident after first touch.
//   Per wave: preload tids (8 x i32x4) -> issue W stripes 0,1 (2-buffer) ->
//   ballot scan (reg-only, covers stripe latency) -> 8-stripe stage stream
//   (f32->f16 + XOR-swizzled write, po = oct ^ (c&7), verified R5/R7/R9) ->
//   per-16-row groups: quarter-pipelined x gather + cvt + 32 MFMA + store.
//   Register audit (R6 lesson): tvv 32 + wrA/wrB 64 + addr ~25 = 121 peak in
//   staging; xqA/xqB 64 + pafA 32 + acc 8 ~ 110 in compute. No spill @ cap 512.

#define NDIM 512
#define KDIM 512
#define NCOL 32
#define LISTCAP 256

typedef _Float16 f16x8 __attribute__((ext_vector_type(8)));
typedef float    f32x4 __attribute__((ext_vector_type(4)));
typedef int      i32x4 __attribute__((ext_vector_type(4)));

__global__ __launch_bounds__(256, 1) void k_wave(
    const float* __restrict__ x,
    const int*   __restrict__ tids,
    const float* __restrict__ W,
    float*       __restrict__ out,
    int n_rows)
{
    const int tid  = threadIdx.x;
    const int lane = tid & 63;
    const int wv   = tid >> 6;
    const int ml   = lane & 15;
    const int q    = lane >> 4;
    const int sc4  = (lane & 7) * 4;    // 4-col group within the 32-col chunk
    const int ol   = lane >> 3;         // lane's base k-octet 0..7

    // unit decode: task's 4 blocks share one XCD (bid&7); 4 waves x 4 block
    // groups cover the task's 16 column chunks.
    const int bid   = blockIdx.x;
    const int task  = (bid & 7) | ((bid >> 5) << 3);
    const int chunk = ((bid >> 3) & 3) * 4 + wv;
    const int c0    = chunk * NCOL;

    __shared__ __align__(16) _Float16 Wt[4][NCOL * KDIM];   // 4 x 32 KB, wave-private
    __shared__ unsigned short rl[4][LISTCAP];               // wave-private row lists

    _Float16*       Wm  = &Wt[wv][0];
    unsigned short* rlm = &rl[wv][0];

    const float* Wg = W + (size_t)task * KDIM * NDIM + c0;

    // ---- preload ALL tids first (oldest in queue: scan consuming them does
    // not force the W stripes to drain)
    i32x4 tvv[8];
    #pragma unroll
    for (int cb = 0; cb < 8; ++cb) {
        const int r4 = cb * 256 + lane * 4;
        if (r4 + 3 < n_rows) {
            tvv[cb] = *(const i32x4*)(tids + r4);
        } else {
            #pragma unroll
            for (int j = 0; j < 4; ++j)
                tvv[cb][j] = (r4 + j < n_rows) ? tids[r4 + j] : -1;
        }
    }

    // ---- W staging helpers: stripe s = k-octets (ol + 8s), rows k = oct*8+j
    float4 wrA[8], wrB[8];
    auto issueS = [&](int s, float4 (&wb)[8]) {
        const size_t kb = (size_t)(ol + 8 * s) * 8;
        #pragma unroll
        for (int j = 0; j < 8; ++j)
            wb[j] = *(const float4*)(Wg + (kb + j) * NDIM + sc4);
    };
    auto stageS = [&](int s, const float4 (&wb)[8]) {
        const int oct = ol + 8 * s;
        #pragma unroll
        for (int j2 = 0; j2 < 4; ++j2) {
            f16x8 h8;
            #pragma unroll
            for (int j = 0; j < 8; ++j)
                h8[j] = (_Float16)(((const float*)&wb[j])[j2]);
            const int c  = sc4 + j2;
            const int po = oct ^ (c & 7);
            *(f16x8*)&Wm[c * KDIM + po * 8] = h8;
        }
    };

    issueS(0, wrA);
    issueS(1, wrB);

    // ---- ballot scan over ALL 2048 rows (register-only; runs under stripe
    // 0/1 HBM latency). Round (cb,j): lanes hold rows cb*256 + lane*4 + j.
    int cnt = 0;
    #pragma unroll
    for (int cb = 0; cb < 8; ++cb) {
        #pragma unroll
        for (int j = 0; j < 4; ++j) {
            const bool m = (tvv[cb][j] == task);
            const unsigned long long bal = __ballot(m);
            const int rank = __popcll(bal & ((1ull << lane) - 1ull));
            const int slot = cnt + rank;
            if (m && slot < LISTCAP) rlm[slot] = (unsigned short)(cb * 256 + lane * 4 + j);
            cnt += __popcll(bal);
        }
    }
    if (cnt > LISTCAP) cnt = LISTCAP;

    // ---- 8-stripe staging stream, 2 live buffers (always one stripe ahead)
    stageS(0, wrA); issueS(2, wrA);
    stageS(1, wrB); issueS(3, wrB);
    stageS(2, wrA); issueS(4, wrA);
    stageS(3, wrB); issueS(5, wrB);
    stageS(4, wrA); issueS(6, wrA);
    stageS(5, wrB); issueS(7, wrB);
    stageS(6, wrA);
    stageS(7, wrB);

    // ---- compute helpers
    f32x4 xqA[8], xqB[8];
    auto issueQ = [&](const float* xr, int qi, f32x4 (&xq)[8]) {
        #pragma unroll
        for (int s = 0; s < 4; ++s) {
            const int ks = qi * 4 + s;
            xq[2 * s]     = *(const f32x4*)(xr + ks * 32 + q * 8);
            xq[2 * s + 1] = *(const f32x4*)(xr + ks * 32 + q * 8 + 4);
        }
    };
    auto cvtQ = [&](const f32x4 (&xq)[8], f16x8* pf) {
        #pragma unroll
        for (int s = 0; s < 4; ++s) {
            f16x8 af;
            const float* a0 = (const float*)&xq[2 * s];
            #pragma unroll
            for (int j = 0; j < 8; ++j) af[j] = (_Float16)a0[j];
            pf[s] = af;
        }
    };
    auto mmaH = [&](int half, const f16x8* pf, f32x4& a0, f32x4& a1) {
        #pragma unroll
        for (int ksl = 0; ksl < 8; ++ksl) {
            const int oct = (half * 8 + ksl) * 4 + q;
            {
                const int po = oct ^ (ml & 7);
                const f16x8 bf = *(const f16x8*)&Wm[ml * KDIM + po * 8];
                a0 = __builtin_amdgcn_mfma_f32_16x16x32_f16(pf[ksl], bf, a0, 0, 0, 0);
            }
            {
                const int cB = 16 + ml;
                const int po = oct ^ (cB & 7);
                const f16x8 bf = *(const f16x8*)&Wm[cB * KDIM + po * 8];
                a1 = __builtin_amdgcn_mfma_f32_16x16x32_f16(pf[ksl], bf, a1, 0, 0, 0);
            }
        }
    };

    // ---- per-16-row groups (avg rows/task = 32 -> ~2 groups), quarter-pipelined
    for (int g0 = 0; g0 < cnt; g0 += 16) {
        const int idx = g0 + ml;
        const int row = rlm[(idx < cnt) ? idx : (cnt - 1)];
        const float* xr = x + (size_t)row * KDIM;

        f16x8 pafA[8], pafB[8];
        f32x4 acc0 = {}, acc1 = {};

        issueQ(xr, 0, xqA);
        issueQ(xr, 1, xqB);
        cvtQ(xqA, pafA);     issueQ(xr, 2, xqA);
        cvtQ(xqB, pafA + 4); issueQ(xr, 3, xqB);
        mmaH(0, pafA, acc0, acc1);          // covers quarters 2,3 in flight
        cvtQ(xqA, pafB);
        cvtQ(xqB, pafB + 4);
        mmaH(1, pafB, acc0, acc1);

        #pragma unroll
        for (int rg = 0; rg < 4; ++rg) {
            const int pos = g0 + q * 4 + rg;
            if (pos < cnt) {
                float* op = out + (size_t)rlm[pos] * NDIM + c0 + ml;
                op[0]  = acc0[rg];
                op[16] = acc1[rg];
            }
        }
    }
}

extern "C" void kernel_launch(void* const* d_in, const int* in_sizes, int n_in,
                              void* d_out, int out_size, void* d_ws, size_t ws_size,
                              hipStream_t stream) {
    const float* x    = (const float*)d_in[0];
    const int*   tids = (const int*)d_in[1];
    const float* W    = (const float*)d_in[2];
    float*       out  = (float*)d_out;
    const int n_rows  = in_sizes[1];   // 2048

    k_wave<<<dim3(256), dim3(256), 0, stream>>>(x, tids, W, out, n_rows);
}